// Round 8
// baseline (241.691 us; speedup 1.0000x reference)
//
#include <hip/hip_runtime.h>
#include <hip/hip_bf16.h>
#include <math.h>

typedef unsigned short u16;

#define BATCH 16384
#define HID   512
#define KDIM  1024   // INPUT + HIDDEN
#define BM    128    // batch rows per block
#define NSTEP 16     // K-steps of 64

typedef __bf16 bf16x8 __attribute__((ext_vector_type(8)));
typedef float  floatx4 __attribute__((ext_vector_type(4)));

__device__ __forceinline__ void async_copy16(const void* g, void* l) {
  __builtin_amdgcn_global_load_lds(
      (const __attribute__((address_space(1))) void*)g,
      (__attribute__((address_space(3))) void*)l, 16, 0, 0);
}

__device__ __forceinline__ float fast_sigmoid(float x) {
  return 1.0f / (1.0f + __expf(-x));
}
__device__ __forceinline__ float fast_tanh(float x) {
  float e = __expf(-2.0f * fabsf(x));
  float t = (1.0f - e) / (1.0f + e);
  return x >= 0.0f ? t : -t;
}
__device__ __forceinline__ u16 f2bf(float f) {
  return __builtin_bit_cast(u16, __float2bfloat16(f));
}

// ---------- pre-pass: fp32 -> bf16 packing (R0's verified kernel) ----------
// Xb: row-major [BATCH][KDIM], X[b] = [prev_h[b] | input_[b]].
// Wf: MFMA-FRAGMENT-MAJOR weights: elem (gate g, per-gate col n, k) at
//   (((g*32 + n/16)*32 + k/32)*64 + ((k>>3)&3)*16 + (n&15))*8 + (k&7)
__global__ __launch_bounds__(256) void pack_kernel(
    const float* __restrict__ input_, const float* __restrict__ prev_h,
    const float* __restrict__ Wi, const float* __restrict__ Wf_,
    const float* __restrict__ Wo, const float* __restrict__ Wg,
    u16* __restrict__ Xb, u16* __restrict__ Wf) {
  int blk = blockIdx.x;
  int k = threadIdx.x * 4;
  if (blk < BATCH) {
    const float* src = (k < HID) ? (prev_h + (size_t)blk * HID + k)
                                 : (input_ + (size_t)blk * HID + (k - HID));
    float4 v = *(const float4*)src;
    ushort4 o;
    o.x = f2bf(v.x); o.y = f2bf(v.y); o.z = f2bf(v.z); o.w = f2bf(v.w);
    *(ushort4*)(Xb + (size_t)blk * KDIM + k) = o;
  } else {
    int grow = blk - BATCH;               // 0..2047, order [Wi|Wf|Wo|Wg]
    int g = grow >> 9;
    int n = grow & (HID - 1);
    const float* s = g == 0 ? Wi : g == 1 ? Wf_ : g == 2 ? Wo : Wg;
    float4 v = *(const float4*)(s + (size_t)n * KDIM + k);
    ushort4 o;
    o.x = f2bf(v.x); o.y = f2bf(v.y); o.z = f2bf(v.z); o.w = f2bf(v.w);
    size_t d = ((size_t)((g * 32 + (n >> 4)) * 32 + (k >> 5)) * 64 +
                ((k >> 3) & 3) * 16 + (n & 15)) * 8 + (k & 7);
    *(ushort4*)(Wf + d) = o;   // k%8 in {0,4} -> 8B-aligned
  }
}

// ---------- main fused GEMM + LSTM epilogue ----------
// R8 = R7's occupancy retile with the buffer race FIXED (distance-1
// prefetch, R0-proven): per-wave acc 128->64 regs, __launch_bounds__(512,4)
// -> 4 waves/SIMD, 2 blocks/CU = 2 independent barrier domains per CU
// (one block's staging overlaps the other's MFMA). Waves: 2 m-halves (wr)
// x 4 n-quarters (wc); per wave 64 rows x 16 cols x 4 gates, acc[4][4].
// Staging = R0's verified global_load_lds (0 regs, 0 VALU; swizzle on the
// GLOBAL source chunk (lane&7)^(row&7), LDS lane-linear; compute reads
// chunk (kk*4+lquad)^(lrow&7)).
// Loop hazard ledger (distance-1):
//   top of S: s_waitcnt vmcnt(8) lgkmcnt(0); s_barrier
//     - vmcnt(8): my fill(buf,S) [2 ops] retired (loadB(S) [8 ops] newer,
//       stays in flight -- T4); uniform, incl. prologue (10 outstanding).
//     - lgkmcnt(0): my step S-1 ds_reads of buf^1 done -> safe to overwrite.
//   fill(buf^1, S+1): buffer whose readers ALL passed this barrier.
//   compute(buf): disjoint from the fill target.
//   loadB(S+1): issued after b's last use (WAR ok), crosses the barrier.
__global__ __launch_bounds__(512, 4) void lstm_gemm_kernel(
    const u16* __restrict__ Xb, const u16* __restrict__ Wf,
    const float* __restrict__ Bi, const float* __restrict__ Bf,
    const float* __restrict__ Bo, const float* __restrict__ Bg,
    const float* __restrict__ prevC, float* __restrict__ out) {
  __shared__ u16 lds[2][8192];   // per buf: 128 rows x 64 elems = 16 KB

  const int tid = threadIdx.x;
  const int wave = tid >> 6, lane = tid & 63;
  const int lrow = lane & 15, lquad = lane >> 4;
  const int wr = wave >> 2, wc = wave & 3;
  const int m_block = blockIdx.y * BM;
  const int ntg = blockIdx.x * 4 + wc;     // per-gate 16-col tile id, 0..31

  // A staging (R0 verified): instr i covers rows li*8+(lane>>3), li=wave*2+i;
  // lane fetches swizzled 16B chunk (l&7)^(l>>3), writes lane-linear.
  const int swz = ((lane & 7) ^ ((lane >> 3) & 7)) * 8;
  const u16* gp[2];
  int lp[2];
#pragma unroll
  for (int i = 0; i < 2; ++i) {
    int li = wave * 2 + i;
    gp[i] = Xb + (size_t)(m_block + li * 8 + (lane >> 3)) * KDIM + swz;
    lp[i] = li * 512;
  }

  floatx4 acc[4][4];   // [gate][m-tile] = 64 AGPRs
#pragma unroll
  for (int g = 0; g < 4; ++g)
#pragma unroll
    for (int mt = 0; mt < 4; ++mt)
      acc[g][mt] = (floatx4){0.f, 0.f, 0.f, 0.f};

  auto fill = [&](int buf, int S) {
#pragma unroll
    for (int i = 0; i < 2; ++i)
      async_copy16(gp[i] + S * 64, &lds[0][0] + buf * 8192 + lp[i]);
  };

  bf16x8 b[2][4];      // single B buffer (32 VGPRs)
  auto loadB = [&](int S) {
#pragma unroll
    for (int kk = 0; kk < 2; ++kk)
#pragma unroll
      for (int g = 0; g < 4; ++g)
        b[kk][g] = *(const bf16x8*)(
            Wf + (((size_t)(g * 32 + ntg) * 32 + (S * 2 + kk)) << 9) +
            lane * 8);
  };

  auto compute = [&](int buf) {
    const u16* LA = &lds[buf][0];
    __builtin_amdgcn_s_setprio(1);
#pragma unroll
    for (int kk = 0; kk < 2; ++kk) {
#pragma unroll
      for (int mt = 0; mt < 4; ++mt) {
        bf16x8 a = *(const bf16x8*)
            &LA[(wr * 64 + mt * 16 + lrow) * 64 +
                (((kk * 4 + lquad) ^ (lrow & 7)) * 8)];
#pragma unroll
        for (int g = 0; g < 4; ++g)
          acc[g][mt] = __builtin_amdgcn_mfma_f32_16x16x32_bf16(
              a, b[kk][g], acc[g][mt], 0, 0, 0);
      }
    }
    __builtin_amdgcn_s_setprio(0);
  };

  // ---- prologue: fill step 0, B(0) ----
  fill(0, 0);
  loadB(0);

  // ---- main loop: one barrier per K-step, counted vmcnt, distance-1 ----
  for (int S = 0; S < NSTEP; ++S) {
    const int buf = S & 1;
    asm volatile("s_waitcnt vmcnt(8) lgkmcnt(0)" ::: "memory");
    __builtin_amdgcn_s_barrier();
    __builtin_amdgcn_sched_barrier(0);
    if (S + 1 < NSTEP) fill(buf ^ 1, S + 1);  // readers passed this barrier
    compute(buf);                             // b waits compiler-counted
    if (S + 1 < NSTEP) loadB(S + 1);          // after b's last use
  }

  // ---- epilogue. C layout (verified): col=lane&15, row=lquad*4+reg ----
  const int j = ntg * 16 + lrow;        // 0..511
  const float vbi = Bi[j], vbf = Bf[j], vbo = Bo[j], vbg = Bg[j];
  float* outH = out;
  float* outC = out + (size_t)BATCH * HID;
#pragma unroll
  for (int mt = 0; mt < 4; ++mt) {
    int rowb = m_block + wr * 64 + mt * 16 + lquad * 4;
#pragma unroll
    for (int rg = 0; rg < 4; ++rg) {
      int row = rowb + rg;
      float gi = fast_sigmoid(acc[0][mt][rg] + vbi);
      float gf = fast_sigmoid(acc[1][mt][rg] + vbf);
      float go = fast_sigmoid(acc[2][mt][rg] + vbo);
      float gg = fast_tanh(acc[3][mt][rg] + vbg);
      float c = gf * prevC[row * HID + j] + gi * gg;
      float h = fast_tanh(c) * go;
      outH[row * HID + j] = h;
      outC[row * HID + j] = c;
    }
  }
}

// ---------- slow fallback if ws too small (correctness insurance) ----------
__global__ void lstm_fallback_kernel(
    const float* __restrict__ input_, const float* __restrict__ prev_h,
    const float* __restrict__ prevC,
    const float* __restrict__ Wi, const float* __restrict__ Bi,
    const float* __restrict__ Wf, const float* __restrict__ Bf,
    const float* __restrict__ Wo, const float* __restrict__ Bo,
    const float* __restrict__ Wg, const float* __restrict__ Bg,
    float* __restrict__ out) {
  int idx = blockIdx.x * blockDim.x + threadIdx.x;
  int b = idx / HID, j = idx % HID;
  if (b >= BATCH) return;
  float si = 0.f, sf = 0.f, so = 0.f, sg = 0.f;
  for (int k = 0; k < KDIM; ++k) {
    float x = (k < HID) ? prev_h[b * HID + k] : input_[b * HID + (k - HID)];
    si += x * Wi[j * KDIM + k];
    sf += x * Wf[j * KDIM + k];
    so += x * Wo[j * KDIM + k];
    sg += x * Wg[j * KDIM + k];
  }
  float gi = fast_sigmoid(si + Bi[j]);
  float gf = fast_sigmoid(sf + Bf[j]);
  float go = fast_sigmoid(so + Bo[j]);
  float gg = fast_tanh(sg + Bg[j]);
  float c = gf * prevC[b * HID + j] + gi * gg;
  out[b * HID + j] = fast_tanh(c) * go;
  out[(size_t)BATCH * HID + b * HID + j] = c;
}

extern "C" void kernel_launch(void* const* d_in, const int* in_sizes, int n_in,
                              void* d_out, int out_size, void* d_ws, size_t ws_size,
                              hipStream_t stream) {
  const float* input_ = (const float*)d_in[0];
  const float* prev_h = (const float*)d_in[1];
  const float* prev_c = (const float*)d_in[2];
  const float* W_i = (const float*)d_in[3];
  const float* b_i = (const float*)d_in[4];
  const float* W_f = (const float*)d_in[5];
  const float* b_f = (const float*)d_in[6];
  const float* W_g = (const float*)d_in[7];
  const float* b_g = (const float*)d_in[8];
  const float* W_o = (const float*)d_in[9];
  const float* b_o = (const float*)d_in[10];
  float* out = (float*)d_out;

  const size_t ws_needed =
      (size_t)BATCH * KDIM * sizeof(u16) + (size_t)4 * HID * KDIM * sizeof(u16);

  if (ws_size < ws_needed) {
    int total = BATCH * HID;
    lstm_fallback_kernel<<<(total + 255) / 256, 256, 0, stream>>>(
        input_, prev_h, prev_c, W_i, b_i, W_f, b_f, W_o, b_o, W_g, b_g, out);
    return;
  }

  u16* Xb = (u16*)d_ws;                       // 16384 x 1024 bf16 = 33.5 MB
  u16* Wfp = Xb + (size_t)BATCH * KDIM;       // fragment-major, 4 MB

  pack_kernel<<<BATCH + 4 * HID, 256, 0, stream>>>(input_, prev_h,
                                                   W_i, W_f, W_o, W_g, Xb, Wfp);

  // grid: x = 8 n-blocks (4 tiles each), y = 128 m-blocks.
  // 1024 blocks x 512 thr at <=128 unified regs/wave -> 2 blocks/CU.
  dim3 grid(8, BATCH / BM);
  lstm_gemm_kernel<<<grid, 512, 0, stream>>>(Xb, Wfp, b_i, b_f, b_o, b_g,
                                             prev_c, out);
}

// Round 9
// 237.618 us; speedup vs baseline: 1.0171x; 1.0171x over previous
//
#include <hip/hip_runtime.h>
#include <hip/hip_bf16.h>
#include <math.h>

typedef unsigned short u16;

#define BATCH 16384
#define HID   512
#define KDIM  1024   // INPUT + HIDDEN
#define BM    128    // batch rows per block
#define NSTEP 16     // K-steps of 64

typedef __bf16 bf16x8 __attribute__((ext_vector_type(8)));
typedef float  floatx4 __attribute__((ext_vector_type(4)));

__device__ __forceinline__ void async_copy16(const void* g, void* l) {
  __builtin_amdgcn_global_load_lds(
      (const __attribute__((address_space(1))) void*)g,
      (__attribute__((address_space(3))) void*)l, 16, 0, 0);
}

__device__ __forceinline__ float fast_sigmoid(float x) {
  return 1.0f / (1.0f + __expf(-x));
}
__device__ __forceinline__ float fast_tanh(float x) {
  float e = __expf(-2.0f * fabsf(x));
  float t = (1.0f - e) / (1.0f + e);
  return x >= 0.0f ? t : -t;
}
__device__ __forceinline__ u16 f2bf(float f) {
  return __builtin_bit_cast(u16, __float2bfloat16(f));
}

// ---------- pre-pass: fp32 -> bf16 packing (R0's verified kernel) ----------
// Xb: row-major [BATCH][KDIM], X[b] = [prev_h[b] | input_[b]].
// Wf: MFMA-FRAGMENT-MAJOR weights: elem (gate g, per-gate col n, k) at
//   (((g*32 + n/16)*32 + k/32)*64 + ((k>>3)&3)*16 + (n&15))*8 + (k&7)
__global__ __launch_bounds__(256) void pack_kernel(
    const float* __restrict__ input_, const float* __restrict__ prev_h,
    const float* __restrict__ Wi, const float* __restrict__ Wf_,
    const float* __restrict__ Wo, const float* __restrict__ Wg,
    u16* __restrict__ Xb, u16* __restrict__ Wf) {
  int blk = blockIdx.x;
  int k = threadIdx.x * 4;
  if (blk < BATCH) {
    const float* src = (k < HID) ? (prev_h + (size_t)blk * HID + k)
                                 : (input_ + (size_t)blk * HID + (k - HID));
    float4 v = *(const float4*)src;
    ushort4 o;
    o.x = f2bf(v.x); o.y = f2bf(v.y); o.z = f2bf(v.z); o.w = f2bf(v.w);
    *(ushort4*)(Xb + (size_t)blk * KDIM + k) = o;
  } else {
    int grow = blk - BATCH;               // 0..2047, order [Wi|Wf|Wo|Wg]
    int g = grow >> 9;
    int n = grow & (HID - 1);
    const float* s = g == 0 ? Wi : g == 1 ? Wf_ : g == 2 ? Wo : Wg;
    float4 v = *(const float4*)(s + (size_t)n * KDIM + k);
    ushort4 o;
    o.x = f2bf(v.x); o.y = f2bf(v.y); o.z = f2bf(v.z); o.w = f2bf(v.w);
    size_t d = ((size_t)((g * 32 + (n >> 4)) * 32 + (k >> 5)) * 64 +
                ((k >> 3) & 3) * 16 + (n & 15)) * 8 + (k & 7);
    *(ushort4*)(Wf + d) = o;   // k%8 in {0,4} -> 8B-aligned
  }
}

// ---------- main fused GEMM + LSTM epilogue ----------
// R9 = R8 (verified) + two latency fixes, no layout changes:
//  1) XCD grid: grid(x=128 m-slabs, y=8 n-siblings); linear dispatch id
//     = x + 128*y -> id%8 == m%8, so all 8 n-siblings of an m-slab land on
//     ONE XCD: the Xb slab is fetched into that L2 once (R8's FETCH was
//     151.7 MB vs ~71 ideal because siblings spread across 8 XCDs).
//  2) 3-buffer LDS ring, DISTANCE-2 fill: fill(S+2) issued at step S,
//     waited at top of S+2 -> ~2 steps of latency cover (>= HBM latency).
// Hazard ledger:
//   top of S: s_waitcnt vmcnt(10) lgkmcnt(0); s_barrier
//     - vmcnt(10): fill(S) retired (younger: fill(S+1)[2]+loadB(S)[8];
//       prologue has 12 outstanding -> drains to 10 ✓).
//     - lgkmcnt(0): my step S-1 ds_reads (of buf (S-1)%3) done.
//   fill((S+2)%3, S+2): target == buf (S-1)%3, ALL readers passed this
//     barrier ✓; disjoint from compute's buf S%3 ✓.
//   loadB(S+1) after b's last use (WAR ok), in flight across barrier (T4).
// Per-wave regs unchanged vs R8 (acc[4][4]=64 AGPR, ~64 VGPR) -> 4
// waves/SIMD; LDS 48 KB -> still 2 blocks/CU.
__global__ __launch_bounds__(512, 4) void lstm_gemm_kernel(
    const u16* __restrict__ Xb, const u16* __restrict__ Wf,
    const float* __restrict__ Bi, const float* __restrict__ Bf,
    const float* __restrict__ Bo, const float* __restrict__ Bg,
    const float* __restrict__ prevC, float* __restrict__ out) {
  __shared__ u16 lds[3][8192];   // ring: 3 x (128 rows x 64 elems) = 48 KB

  const int tid = threadIdx.x;
  const int wave = tid >> 6, lane = tid & 63;
  const int lrow = lane & 15, lquad = lane >> 4;
  const int wr = wave >> 2, wc = wave & 3;
  const int m_block = blockIdx.x * BM;     // x = m-slab (XCD-locality key)
  const int ntg = blockIdx.y * 4 + wc;     // per-gate 16-col tile id, 0..31

  // A staging (R0 verified): instr i covers rows li*8+(lane>>3), li=wave*2+i;
  // lane fetches swizzled 16B chunk (l&7)^(l>>3), writes lane-linear.
  const int swz = ((lane & 7) ^ ((lane >> 3) & 7)) * 8;
  const u16* gp[2];
  int lp[2];
#pragma unroll
  for (int i = 0; i < 2; ++i) {
    int li = wave * 2 + i;
    gp[i] = Xb + (size_t)(m_block + li * 8 + (lane >> 3)) * KDIM + swz;
    lp[i] = li * 512;
  }

  floatx4 acc[4][4];   // [gate][m-tile] = 64 AGPRs
#pragma unroll
  for (int g = 0; g < 4; ++g)
#pragma unroll
    for (int mt = 0; mt < 4; ++mt)
      acc[g][mt] = (floatx4){0.f, 0.f, 0.f, 0.f};

  auto fill = [&](int buf, int S) {
#pragma unroll
    for (int i = 0; i < 2; ++i)
      async_copy16(gp[i] + S * 64, &lds[0][0] + buf * 8192 + lp[i]);
  };

  bf16x8 b[2][4];      // single B buffer (32 VGPRs)
  auto loadB = [&](int S) {
#pragma unroll
    for (int kk = 0; kk < 2; ++kk)
#pragma unroll
      for (int g = 0; g < 4; ++g)
        b[kk][g] = *(const bf16x8*)(
            Wf + (((size_t)(g * 32 + ntg) * 32 + (S * 2 + kk)) << 9) +
            lane * 8);
  };

  auto compute = [&](int buf) {
    const u16* LA = &lds[buf][0];
    __builtin_amdgcn_s_setprio(1);
#pragma unroll
    for (int kk = 0; kk < 2; ++kk) {
#pragma unroll
      for (int mt = 0; mt < 4; ++mt) {
        bf16x8 a = *(const bf16x8*)
            &LA[(wr * 64 + mt * 16 + lrow) * 64 +
                (((kk * 4 + lquad) ^ (lrow & 7)) * 8)];
#pragma unroll
        for (int g = 0; g < 4; ++g)
          acc[g][mt] = __builtin_amdgcn_mfma_f32_16x16x32_bf16(
              a, b[kk][g], acc[g][mt], 0, 0, 0);
      }
    }
    __builtin_amdgcn_s_setprio(0);
  };

  // ---- prologue: fills for steps 0,1; B(0) ----
  fill(0, 0);
  fill(1, 1);
  loadB(0);

  // ---- main loop: one barrier per K-step, counted vmcnt, distance-2 ----
#pragma unroll
  for (int S = 0; S < NSTEP; ++S) {
    asm volatile("s_waitcnt vmcnt(10) lgkmcnt(0)" ::: "memory");
    __builtin_amdgcn_s_barrier();
    __builtin_amdgcn_sched_barrier(0);
    if (S + 2 < NSTEP) fill((S + 2) % 3, S + 2);  // = buf (S-1)%3, safe
    compute(S % 3);                               // b waits compiler-counted
    if (S + 1 < NSTEP) loadB(S + 1);              // after b's last use
  }

  // ---- epilogue. C layout (verified): col=lane&15, row=lquad*4+reg ----
  const int j = ntg * 16 + lrow;        // 0..511
  const float vbi = Bi[j], vbf = Bf[j], vbo = Bo[j], vbg = Bg[j];
  float* outH = out;
  float* outC = out + (size_t)BATCH * HID;
#pragma unroll
  for (int mt = 0; mt < 4; ++mt) {
    int rowb = m_block + wr * 64 + mt * 16 + lquad * 4;
#pragma unroll
    for (int rg = 0; rg < 4; ++rg) {
      int row = rowb + rg;
      float gi = fast_sigmoid(acc[0][mt][rg] + vbi);
      float gf = fast_sigmoid(acc[1][mt][rg] + vbf);
      float go = fast_sigmoid(acc[2][mt][rg] + vbo);
      float gg = fast_tanh(acc[3][mt][rg] + vbg);
      float c = gf * prevC[row * HID + j] + gi * gg;
      float h = fast_tanh(c) * go;
      outH[row * HID + j] = h;
      outC[row * HID + j] = c;
    }
  }
}

// ---------- slow fallback if ws too small (correctness insurance) ----------
__global__ void lstm_fallback_kernel(
    const float* __restrict__ input_, const float* __restrict__ prev_h,
    const float* __restrict__ prevC,
    const float* __restrict__ Wi, const float* __restrict__ Bi,
    const float* __restrict__ Wf, const float* __restrict__ Bf,
    const float* __restrict__ Wo, const float* __restrict__ Bo,
    const float* __restrict__ Wg, const float* __restrict__ Bg,
    float* __restrict__ out) {
  int idx = blockIdx.x * blockDim.x + threadIdx.x;
  int b = idx / HID, j = idx % HID;
  if (b >= BATCH) return;
  float si = 0.f, sf = 0.f, so = 0.f, sg = 0.f;
  for (int k = 0; k < KDIM; ++k) {
    float x = (k < HID) ? prev_h[b * HID + k] : input_[b * HID + (k - HID)];
    si += x * Wi[j * KDIM + k];
    sf += x * Wf[j * KDIM + k];
    so += x * Wo[j * KDIM + k];
    sg += x * Wg[j * KDIM + k];
  }
  float gi = fast_sigmoid(si + Bi[j]);
  float gf = fast_sigmoid(sf + Bf[j]);
  float go = fast_sigmoid(so + Bo[j]);
  float gg = fast_tanh(sg + Bg[j]);
  float c = gf * prevC[b * HID + j] + gi * gg;
  out[b * HID + j] = fast_tanh(c) * go;
  out[(size_t)BATCH * HID + b * HID + j] = c;
}

extern "C" void kernel_launch(void* const* d_in, const int* in_sizes, int n_in,
                              void* d_out, int out_size, void* d_ws, size_t ws_size,
                              hipStream_t stream) {
  const float* input_ = (const float*)d_in[0];
  const float* prev_h = (const float*)d_in[1];
  const float* prev_c = (const float*)d_in[2];
  const float* W_i = (const float*)d_in[3];
  const float* b_i = (const float*)d_in[4];
  const float* W_f = (const float*)d_in[5];
  const float* b_f = (const float*)d_in[6];
  const float* W_g = (const float*)d_in[7];
  const float* b_g = (const float*)d_in[8];
  const float* W_o = (const float*)d_in[9];
  const float* b_o = (const float*)d_in[10];
  float* out = (float*)d_out;

  const size_t ws_needed =
      (size_t)BATCH * KDIM * sizeof(u16) + (size_t)4 * HID * KDIM * sizeof(u16);

  if (ws_size < ws_needed) {
    int total = BATCH * HID;
    lstm_fallback_kernel<<<(total + 255) / 256, 256, 0, stream>>>(
        input_, prev_h, prev_c, W_i, b_i, W_f, b_f, W_o, b_o, W_g, b_g, out);
    return;
  }

  u16* Xb = (u16*)d_ws;                       // 16384 x 1024 bf16 = 33.5 MB
  u16* Wfp = Xb + (size_t)BATCH * KDIM;       // fragment-major, 4 MB

  pack_kernel<<<BATCH + 4 * HID, 256, 0, stream>>>(input_, prev_h,
                                                   W_i, W_f, W_o, W_g, Xb, Wfp);

  // grid: x = 128 m-slabs, y = 8 n-siblings. Linear id = x + 128*y ->
  // id%8 = m%8: all 8 n-siblings of an m-slab land on one XCD (L2 reuse).
  dim3 grid(BATCH / BM, 8);
  lstm_gemm_kernel<<<grid, 512, 0, stream>>>(Xb, Wfp, b_i, b_f, b_o, b_g,
                                             prev_c, out);
}